// Round 15
// baseline (47.543 us; speedup 1.0000x reference)
//
#include <hip/hip_runtime.h>
#include <hip/hip_bf16.h>

#define N_ROWS 8192
#define DIM 128
#define MARGIN_F 0.3f

typedef __attribute__((ext_vector_type(8))) short short8;
typedef __attribute__((ext_vector_type(4))) float f32x4;

// ---------------- Kernel A: fp32 -> bf16 (fragment-major), norms, init ----
// Fragment-major layout: 16B unit u = c16*256 + kk*64 + l4*16 + l15 holds
// bf16 elems [kk*32 + l4*8 .. +8) of row (c16*16 + l15). An MFMA A/B-fragment
// load for 16-row panel c16 is xf[c16*256 + kk*64 + lane]: 64 lanes contiguous.
// xbA holds -2*x (exact bf16 pow2 scale) so seeding acc with sqc makes the
// MFMA emit v = sqc - 2*s directly (epilogue: no add).
__global__ __launch_bounds__(256) void prep_kernel(
    const float* __restrict__ x, const int* __restrict__ tgt,
    unsigned short* __restrict__ xbA, unsigned short* __restrict__ xbB,
    float2* __restrict__ meta, int* __restrict__ apb, int* __restrict__ anb,
    unsigned long long* __restrict__ lsum, unsigned int* __restrict__ lcnt) {
  if (blockIdx.x == 0 && threadIdx.x == 0) { *lsum = 0ull; *lcnt = 0u; }
  const int w = threadIdx.x >> 6, l = threadIdx.x & 63;
  const int row = blockIdx.x * 4 + w;
  float2 v = reinterpret_cast<const float2*>(x + (size_t)row * DIM)[l];
  __hip_bfloat16 b0 = __float2bfloat16(v.x);
  __hip_bfloat16 b1 = __float2bfloat16(v.y);
  __hip_bfloat16 a0 = __float2bfloat16(-2.f * v.x);
  __hip_bfloat16 a1 = __float2bfloat16(-2.f * v.y);
  ushort2 stB, stA;
  stB.x = *reinterpret_cast<unsigned short*>(&b0);
  stB.y = *reinterpret_cast<unsigned short*>(&b1);
  stA.x = *reinterpret_cast<unsigned short*>(&a0);
  stA.y = *reinterpret_cast<unsigned short*>(&a1);
  const int c16 = row >> 4, l15r = row & 15;
  const int unit = c16 * 256 + (l >> 4) * 64 + ((l >> 2) & 3) * 16 + l15r;
  reinterpret_cast<ushort2*>(xbB)[unit * 4 + (l & 3)] = stB;
  reinterpret_cast<ushort2*>(xbA)[unit * 4 + (l & 3)] = stA;

  float s = v.x * v.x + v.y * v.y;
  #pragma unroll
  for (int off = 32; off >= 1; off >>= 1) s += __shfl_xor(s, off);
  if (l == 0) {
    float2 m;
    m.x = s;
    m.y = __int_as_float(tgt[row]);   // raw bit carry; only ever bit-compared
    meta[row] = m;
    apb[row] = 0x00000000;            // 0.0f (max identity; diagonal is positive)
    anb[row] = 0x7f800000;            // +inf (min identity)
  }
}

// ---------------- Kernel B: fused Gram + mining, DUAL-STREAM MLP -----------
// NO LDS, NO barriers. grid (64,8) = 512 blocks = 2/CU, one clean generation.
// Each wave: 32 rows x TWO independent 512-col streams (u,v), 16 tiles each.
// Schedule per tile: MFMA_u -> PREF_u(t+1) -> MFMA_v -> PREF_v(t+1) ->
// EPI_u -> EPI_v. Each stream's loads are covered by the OTHER stream's full
// MFMA cluster + both epilogues (~700+ cyc) — genuine memory-level
// parallelism across independent register state, not one dependence chain.
// Meta ping-pongs (m*0/m*1) so EPI's class word survives the prefetch.
__global__ __launch_bounds__(256, 2) void gram_mine_kernel(
    const unsigned short* __restrict__ xbA, const unsigned short* __restrict__ xbB,
    const float2* __restrict__ meta, int* __restrict__ apb, int* __restrict__ anb) {
  const int t = threadIdx.x;
  const int w = t >> 6, l = t & 63;
  const int l15 = l & 15, l4 = l >> 4;
  const int rb = blockIdx.x * 128 + w * 32;      // wave's global row base
  const int cu = blockIdx.y * 1024;              // stream u cols [cu, cu+512)
  const int cv = cu + 512;                       // stream v cols [cv, cv+512)

  const short8* xfA = reinterpret_cast<const short8*>(xbA);
  const short8* xfB = reinterpret_cast<const short8*>(xbB);

  // A fragments (-2x): panels (rb>>4), (rb>>4)+1 (rows rb..rb+31)
  short8 a0[4], a1[4];
  #pragma unroll
  for (int kk = 0; kk < 4; ++kk) {
    a0[kk] = xfA[(rb >> 4) * 256 + kk * 64 + l];
    a1[kk] = xfA[((rb >> 4) + 1) * 256 + kk * 64 + l];
  }

  // per-lane row classes (C/D layout rows: rb + rf*16 + l4*4 + rg)
  int t_r[8];
  #pragma unroll
  for (int rf = 0; rf < 2; ++rf)
    #pragma unroll
    for (int rg = 0; rg < 4; ++rg)
      t_r[rf * 4 + rg] = __float_as_int(meta[rb + rf * 16 + l4 * 4 + rg].y);

  // mining state on v = sqc - 2*s (row term +sq_r deferred to the end)
  float ap2[8], an2[8];
  #pragma unroll
  for (int i = 0; i < 8; ++i) { ap2[i] = -__builtin_inff(); an2[i] = __builtin_inff(); }

  // per-stream single B buffer + ping-pong meta; all names static (rule #20)
  short8 bu[8], bv[8];
  float2 mu0[2], mu1[2], mv0[2], mv1[2];
  f32x4 accu[2][2], accv[2][2];

#define PREF(BASE, IDX, BB, MC) do {                                          \
    const int cb16_ = ((BASE) >> 4) + (IDX) * 2;                              \
    _Pragma("unroll")                                                         \
    for (int kk_ = 0; kk_ < 4; ++kk_) {                                       \
      BB[kk_ * 2 + 0] = xfB[(cb16_ + 0) * 256 + kk_ * 64 + l];                \
      BB[kk_ * 2 + 1] = xfB[(cb16_ + 1) * 256 + kk_ * 64 + l];                \
    }                                                                         \
    MC[0] = meta[(BASE) + (IDX) * 32 + l15];                                  \
    MC[1] = meta[(BASE) + (IDX) * 32 + 16 + l15]; } while (0)

#define MFMA_T(BB, MC, ACC) do {                                              \
    _Pragma("unroll")                                                         \
    for (int cf_ = 0; cf_ < 2; ++cf_) {                                       \
      float s_ = MC[cf_].x;                                                   \
      f32x4 ci_ = {s_, s_, s_, s_};                                           \
      ACC[0][cf_] = ci_; ACC[1][cf_] = ci_;                                   \
    }                                                                         \
    __builtin_amdgcn_s_setprio(1);                                            \
    _Pragma("unroll")                                                         \
    for (int kk_ = 0; kk_ < 4; ++kk_) {                                       \
      _Pragma("unroll")                                                       \
      for (int cf_ = 0; cf_ < 2; ++cf_) {                                     \
        ACC[0][cf_] = __builtin_amdgcn_mfma_f32_16x16x32_bf16(                \
            a0[kk_], BB[kk_ * 2 + cf_], ACC[0][cf_], 0, 0, 0);                \
        ACC[1][cf_] = __builtin_amdgcn_mfma_f32_16x16x32_bf16(                \
            a1[kk_], BB[kk_ * 2 + cf_], ACC[1][cf_], 0, 0, 0);                \
      } }                                                                     \
    __builtin_amdgcn_s_setprio(0); } while (0)

#define EPI_T(ACC, MC) do {                                                   \
    _Pragma("unroll")                                                         \
    for (int cf_ = 0; cf_ < 2; ++cf_) {                                       \
      const int tc_ = __float_as_int(MC[cf_].y);                              \
      _Pragma("unroll")                                                       \
      for (int rf_ = 0; rf_ < 2; ++rf_) {                                     \
        _Pragma("unroll")                                                     \
        for (int rg_ = 0; rg_ < 4; ++rg_) {                                   \
          const int ix_ = rf_ * 4 + rg_;                                      \
          float v_ = ACC[rf_][cf_][rg_];                                      \
          bool p_ = (t_r[ix_] == tc_);                                        \
          ap2[ix_] = p_ ? fmaxf(ap2[ix_], v_) : ap2[ix_];                     \
          an2[ix_] = p_ ? an2[ix_] : fminf(an2[ix_], v_);                     \
        } } } } while (0)

  // prologue: both streams' tile 0 in flight
  PREF(cu, 0, bu, mu0);
  PREF(cv, 0, bv, mv0);

  // 16 tiles per stream, unrolled x2 for static meta parity
  #pragma unroll 1
  for (int q = 0; q < 8; ++q) {
    const int te = 2 * q;                       // even tile (meta parity 0)
    const int n1 = te + 1;                      // next tile
    const int n2 = (te + 2 < 16) ? te + 2 : 15; // clamped (dead reload at end)
    // even tile: consume parity-0 meta, prefetch into parity-1
    MFMA_T(bu, mu0, accu); PREF(cu, n1, bu, mu1);
    MFMA_T(bv, mv0, accv); PREF(cv, n1, bv, mv1);
    EPI_T(accu, mu0); EPI_T(accv, mv0);
    // odd tile: consume parity-1 meta, prefetch into parity-0
    MFMA_T(bu, mu1, accu); PREF(cu, n2, bu, mu0);
    MFMA_T(bv, mv1, accv); PREF(cv, n2, bv, mv0);
    EPI_T(accu, mu1); EPI_T(accv, mv1);
  }

#undef PREF
#undef MFMA_T
#undef EPI_T

  // reduce across the 16 lanes (same l4 group = same rows, different cols)
  #pragma unroll
  for (int i = 0; i < 8; ++i) {
    #pragma unroll
    for (int off = 1; off < 16; off <<= 1) {
      ap2[i] = fmaxf(ap2[i], __shfl_xor(ap2[i], off));
      an2[i] = fminf(an2[i], __shfl_xor(an2[i], off));
    }
  }
  if (l15 == 0) {
    #pragma unroll
    for (int rf = 0; rf < 2; ++rf)
      #pragma unroll
      for (int rg = 0; rg < 4; ++rg) {
        int row = rb + rf * 16 + l4 * 4 + rg;
        float sqr = meta[row].x;
        // d^2 = v + sq_r; clamp >=1e-12 commutes with max/min; non-negative
        // floats are int-monotone -> int atomics give exact fp max/min.
        float a2 = fmaxf(ap2[rf * 4 + rg] + sqr, 1e-12f);
        float n2 = fmaxf(an2[rf * 4 + rg] + sqr, 1e-12f);
        atomicMax(apb + row, __float_as_int(a2));
        atomicMin(anb + row, __float_as_int(n2));
      }
  }
}

// ---------------- Kernel C: multi-block deterministic loss -----------------
// 8 blocks x 1024 thr, 1 row/thread. Partial sums accumulate via int64
// fixed-point (x 2^22) atomicAdd — integer addition is order-independent, so
// the result is bit-deterministic across replays. Last block writes d_out.
__global__ __launch_bounds__(1024) void loss_kernel(
    const int* __restrict__ apb, const int* __restrict__ anb,
    unsigned long long* __restrict__ lsum, unsigned int* __restrict__ lcnt,
    float* __restrict__ out) {
  __shared__ float red[16];
  const int i = blockIdx.x * 1024 + threadIdx.x;
  float ap = sqrtf(__int_as_float(apb[i]));
  float an = sqrtf(__int_as_float(anb[i]));     // +inf sentinel -> relu(-inf)=0
  float li = ap - an + MARGIN_F;
  float s = li > 0.f ? li : 0.f;
  #pragma unroll
  for (int off = 32; off >= 1; off >>= 1) s += __shfl_xor(s, off);
  const int w = threadIdx.x >> 6, l = threadIdx.x & 63;
  if (l == 0) red[w] = s;
  __syncthreads();
  if (threadIdx.x < 16) {
    float v = red[threadIdx.x];
    #pragma unroll
    for (int off = 8; off >= 1; off >>= 1) v += __shfl_xor(v, off);
    if (threadIdx.x == 0) {
      unsigned long long q = (unsigned long long)(long long)((double)v * 4194304.0);
      atomicAdd(lsum, q);
      __threadfence();
      unsigned int old = atomicAdd(lcnt, 1u);
      if (old == gridDim.x - 1) {
        unsigned long long tot = atomicAdd(lsum, 0ull);
        out[0] = (float)((double)tot * (1.0 / 4194304.0) / (double)N_ROWS);
      }
    }
  }
}

extern "C" void kernel_launch(void* const* d_in, const int* in_sizes, int n_in,
                              void* d_out, int out_size, void* d_ws, size_t ws_size,
                              hipStream_t stream) {
  const float* x = (const float*)d_in[0];
  const int* tgt = (const int*)d_in[1];
  float* out = (float*)d_out;

  char* ws = (char*)d_ws;
  unsigned short* xbA = (unsigned short*)ws;                // 2 MB frag-major -2x
  unsigned short* xbB = (unsigned short*)(ws + 2097152);    // 2 MB frag-major  x
  float2* meta = (float2*)(ws + 4194304);                   // 64 KB (sq, tgt)
  int* apb = (int*)(ws + 4259840);                          // 32 KB ap^2 bits
  int* anb = (int*)(ws + 4292608);                          // 32 KB an^2 bits
  unsigned long long* lsum = (unsigned long long*)(ws + 4325376);
  unsigned int* lcnt = (unsigned int*)(ws + 4325384);

  prep_kernel<<<2048, 256, 0, stream>>>(x, tgt, xbA, xbB, meta, apb, anb, lsum, lcnt);
  gram_mine_kernel<<<dim3(64, 8), 256, 0, stream>>>(xbA, xbB, meta, apb, anb);
  loss_kernel<<<8, 1024, 0, stream>>>(apb, anb, lsum, lcnt, out);
}

// Round 16
// 46.547 us; speedup vs baseline: 1.0214x; 1.0214x over previous
//
#include <hip/hip_runtime.h>
#include <hip/hip_bf16.h>

#define N_ROWS 8192
#define DIM 128
#define MARGIN_F 0.3f

typedef __attribute__((ext_vector_type(8))) short short8;
typedef __attribute__((ext_vector_type(4))) float f32x4;

// ---------------- Kernel A: fp32 -> bf16 (fragment-major), norms, init ----
// Fragment-major layout: 16B unit u = c16*256 + kk*64 + l4*16 + l15 holds
// bf16 elems [kk*32 + l4*8 .. +8) of row (c16*16 + l15). An MFMA A/B-fragment
// load for 16-row panel c16 is xf[c16*256 + kk*64 + lane]: 64 lanes contiguous.
// xbA holds -2*x (exact bf16 pow2 scale) so seeding acc with sqc makes the
// MFMA emit v = sqc - 2*s directly (epilogue: no add).
__global__ __launch_bounds__(256) void prep_kernel(
    const float* __restrict__ x, const int* __restrict__ tgt,
    unsigned short* __restrict__ xbA, unsigned short* __restrict__ xbB,
    float2* __restrict__ meta, int* __restrict__ apb, int* __restrict__ anb,
    unsigned long long* __restrict__ lsum, unsigned int* __restrict__ lcnt) {
  if (blockIdx.x == 0 && threadIdx.x == 0) { *lsum = 0ull; *lcnt = 0u; }
  const int w = threadIdx.x >> 6, l = threadIdx.x & 63;
  const int row = blockIdx.x * 4 + w;
  float2 v = reinterpret_cast<const float2*>(x + (size_t)row * DIM)[l];
  __hip_bfloat16 b0 = __float2bfloat16(v.x);
  __hip_bfloat16 b1 = __float2bfloat16(v.y);
  __hip_bfloat16 a0 = __float2bfloat16(-2.f * v.x);
  __hip_bfloat16 a1 = __float2bfloat16(-2.f * v.y);
  ushort2 stB, stA;
  stB.x = *reinterpret_cast<unsigned short*>(&b0);
  stB.y = *reinterpret_cast<unsigned short*>(&b1);
  stA.x = *reinterpret_cast<unsigned short*>(&a0);
  stA.y = *reinterpret_cast<unsigned short*>(&a1);
  const int c16 = row >> 4, l15r = row & 15;
  const int unit = c16 * 256 + (l >> 4) * 64 + ((l >> 2) & 3) * 16 + l15r;
  reinterpret_cast<ushort2*>(xbB)[unit * 4 + (l & 3)] = stB;
  reinterpret_cast<ushort2*>(xbA)[unit * 4 + (l & 3)] = stA;

  float s = v.x * v.x + v.y * v.y;
  #pragma unroll
  for (int off = 32; off >= 1; off >>= 1) s += __shfl_xor(s, off);
  if (l == 0) {
    float2 m;
    m.x = s;
    m.y = __int_as_float(tgt[row]);   // raw bit carry; only ever bit-compared
    meta[row] = m;
    apb[row] = 0x00000000;            // 0.0f (max identity; diagonal is positive)
    anb[row] = 0x7f800000;            // +inf (min identity)
  }
}

// ---------------- Kernel B: fused Gram + mining, MAX-TLP -------------------
// NO LDS, NO barriers, NO manual pipelining. grid (64,32) = 2048 blocks x 4
// waves = 8192 waves = 8/SIMD queued; __launch_bounds__(256,4) caps VGPR at
// 128 -> 4 waves/SIMD RESIDENT (2 clean generations). Every previous round
// ran at 2 waves/SIMD with hand-rolled in-wave pipelines; this round gives
// the hardware scheduler 4 independent waves per SIMD to hide load latency
// and MFMA dependent-chain bubbles across waves. Wave = 32 rows x 32 cols
// per tile, 8 tiles (256-col chunk), tile loop fully unrolled so the
// compiler may hoist next-tile loads as registers allow.
__global__ __launch_bounds__(256, 4) void gram_mine_kernel(
    const unsigned short* __restrict__ xbA, const unsigned short* __restrict__ xbB,
    const float2* __restrict__ meta, int* __restrict__ apb, int* __restrict__ anb) {
  const int t = threadIdx.x;
  const int w = t >> 6, l = t & 63;
  const int l15 = l & 15, l4 = l >> 4;
  const int rb = blockIdx.x * 128 + w * 32;      // wave's global row base
  const int chunk = blockIdx.y * 256;            // 256 cols per chunk (8 tiles)
  const int chunkb = chunk >> 4;

  const short8* xfA = reinterpret_cast<const short8*>(xbA);
  const short8* xfB = reinterpret_cast<const short8*>(xbB);

  // A fragments (-2x): panels (rb>>4), (rb>>4)+1 (rows rb..rb+31)
  short8 a0[4], a1[4];
  #pragma unroll
  for (int kk = 0; kk < 4; ++kk) {
    a0[kk] = xfA[(rb >> 4) * 256 + kk * 64 + l];
    a1[kk] = xfA[((rb >> 4) + 1) * 256 + kk * 64 + l];
  }

  // per-lane row classes (C/D layout rows: rb + rf*16 + l4*4 + rg)
  int t_r[8];
  #pragma unroll
  for (int rf = 0; rf < 2; ++rf)
    #pragma unroll
    for (int rg = 0; rg < 4; ++rg)
      t_r[rf * 4 + rg] = __float_as_int(meta[rb + rf * 16 + l4 * 4 + rg].y);

  // mining state on v = sqc - 2*s (row term +sq_r deferred to the end)
  float ap2[8], an2[8];
  #pragma unroll
  for (int i = 0; i < 8; ++i) { ap2[i] = -__builtin_inff(); an2[i] = __builtin_inff(); }

  #pragma unroll
  for (int ct = 0; ct < 8; ++ct) {
    const int cb16 = chunkb + ct * 2;

    // tile loads: 8 B fragments + 2 meta (compiler schedules/hoists freely)
    short8 b[8];
    #pragma unroll
    for (int kk = 0; kk < 4; ++kk) {
      b[kk * 2 + 0] = xfB[(cb16 + 0) * 256 + kk * 64 + l];
      b[kk * 2 + 1] = xfB[(cb16 + 1) * 256 + kk * 64 + l];
    }
    float2 mc0 = meta[chunk + ct * 32 + l15];
    float2 mc1 = meta[chunk + ct * 32 + 16 + l15];

    // acc seeded with sqc: MFMA (-2x A) emits v = sqc - 2s directly
    f32x4 acc[2][2];
    {
      f32x4 c0 = {mc0.x, mc0.x, mc0.x, mc0.x};
      f32x4 c1 = {mc1.x, mc1.x, mc1.x, mc1.x};
      acc[0][0] = c0; acc[1][0] = c0;
      acc[0][1] = c1; acc[1][1] = c1;
    }

    __builtin_amdgcn_s_setprio(1);
    #pragma unroll
    for (int kk = 0; kk < 4; ++kk) {
      #pragma unroll
      for (int cf = 0; cf < 2; ++cf) {
        acc[0][cf] = __builtin_amdgcn_mfma_f32_16x16x32_bf16(
            a0[kk], b[kk * 2 + cf], acc[0][cf], 0, 0, 0);
        acc[1][cf] = __builtin_amdgcn_mfma_f32_16x16x32_bf16(
            a1[kk], b[kk * 2 + cf], acc[1][cf], 0, 0, 0);
      }
    }
    __builtin_amdgcn_s_setprio(0);

    // mining epilogue
    #pragma unroll
    for (int cf = 0; cf < 2; ++cf) {
      const int tc = __float_as_int(cf == 0 ? mc0.y : mc1.y);
      #pragma unroll
      for (int rf = 0; rf < 2; ++rf)
        #pragma unroll
        for (int rg = 0; rg < 4; ++rg) {
          const int ix = rf * 4 + rg;
          float v = acc[rf][cf][rg];
          bool p = (t_r[ix] == tc);
          ap2[ix] = p ? fmaxf(ap2[ix], v) : ap2[ix];
          an2[ix] = p ? an2[ix] : fminf(an2[ix], v);
        }
    }
  }

  // reduce across the 16 lanes (same l4 group = same rows, different cols)
  #pragma unroll
  for (int i = 0; i < 8; ++i) {
    #pragma unroll
    for (int off = 1; off < 16; off <<= 1) {
      ap2[i] = fmaxf(ap2[i], __shfl_xor(ap2[i], off));
      an2[i] = fminf(an2[i], __shfl_xor(an2[i], off));
    }
  }
  if (l15 == 0) {
    #pragma unroll
    for (int rf = 0; rf < 2; ++rf)
      #pragma unroll
      for (int rg = 0; rg < 4; ++rg) {
        int row = rb + rf * 16 + l4 * 4 + rg;
        float sqr = meta[row].x;
        // d^2 = v + sq_r; clamp >=1e-12 commutes with max/min; non-negative
        // floats are int-monotone -> int atomics give exact fp max/min.
        float a2 = fmaxf(ap2[rf * 4 + rg] + sqr, 1e-12f);
        float n2 = fmaxf(an2[rf * 4 + rg] + sqr, 1e-12f);
        atomicMax(apb + row, __float_as_int(a2));
        atomicMin(anb + row, __float_as_int(n2));
      }
  }
}

// ---------------- Kernel C: multi-block deterministic loss -----------------
// 8 blocks x 1024 thr, 1 row/thread. Partial sums accumulate via int64
// fixed-point (x 2^22) atomicAdd — integer addition is order-independent, so
// the result is bit-deterministic across replays. Last block writes d_out.
__global__ __launch_bounds__(1024) void loss_kernel(
    const int* __restrict__ apb, const int* __restrict__ anb,
    unsigned long long* __restrict__ lsum, unsigned int* __restrict__ lcnt,
    float* __restrict__ out) {
  __shared__ float red[16];
  const int i = blockIdx.x * 1024 + threadIdx.x;
  float ap = sqrtf(__int_as_float(apb[i]));
  float an = sqrtf(__int_as_float(anb[i]));     // +inf sentinel -> relu(-inf)=0
  float li = ap - an + MARGIN_F;
  float s = li > 0.f ? li : 0.f;
  #pragma unroll
  for (int off = 32; off >= 1; off >>= 1) s += __shfl_xor(s, off);
  const int w = threadIdx.x >> 6, l = threadIdx.x & 63;
  if (l == 0) red[w] = s;
  __syncthreads();
  if (threadIdx.x < 16) {
    float v = red[threadIdx.x];
    #pragma unroll
    for (int off = 8; off >= 1; off >>= 1) v += __shfl_xor(v, off);
    if (threadIdx.x == 0) {
      unsigned long long q = (unsigned long long)(long long)((double)v * 4194304.0);
      atomicAdd(lsum, q);
      __threadfence();
      unsigned int old = atomicAdd(lcnt, 1u);
      if (old == gridDim.x - 1) {
        unsigned long long tot = atomicAdd(lsum, 0ull);
        out[0] = (float)((double)tot * (1.0 / 4194304.0) / (double)N_ROWS);
      }
    }
  }
}

extern "C" void kernel_launch(void* const* d_in, const int* in_sizes, int n_in,
                              void* d_out, int out_size, void* d_ws, size_t ws_size,
                              hipStream_t stream) {
  const float* x = (const float*)d_in[0];
  const int* tgt = (const int*)d_in[1];
  float* out = (float*)d_out;

  char* ws = (char*)d_ws;
  unsigned short* xbA = (unsigned short*)ws;                // 2 MB frag-major -2x
  unsigned short* xbB = (unsigned short*)(ws + 2097152);    // 2 MB frag-major  x
  float2* meta = (float2*)(ws + 4194304);                   // 64 KB (sq, tgt)
  int* apb = (int*)(ws + 4259840);                          // 32 KB ap^2 bits
  int* anb = (int*)(ws + 4292608);                          // 32 KB an^2 bits
  unsigned long long* lsum = (unsigned long long*)(ws + 4325376);
  unsigned int* lcnt = (unsigned int*)(ws + 4325384);

  prep_kernel<<<2048, 256, 0, stream>>>(x, tgt, xbA, xbB, meta, apb, anb, lsum, lcnt);
  gram_mine_kernel<<<dim3(64, 32), 256, 0, stream>>>(xbA, xbB, meta, apb, anb);
  loss_kernel<<<8, 1024, 0, stream>>>(apb, anb, lsum, lcnt, out);
}